// Round 1
// baseline (417.866 us; speedup 1.0000x reference)
//
#include <hip/hip_runtime.h>

#define B_  2048
#define S_  512
#define F_  64
#define H_  32
#define G_  128   // 4*H

__device__ __forceinline__ void gload_lds4(const float* g, float* l) {
    __builtin_amdgcn_global_load_lds(
        (const __attribute__((address_space(1))) void*)g,
        (__attribute__((address_space(3))) void*)l,
        4, 0, 0);
}

__global__ __launch_bounds__(64, 2)
void lstm_mlp_kernel(const float* __restrict__ x,
                     const float* __restrict__ Wx,
                     const float* __restrict__ Wh,
                     const float* __restrict__ bg,
                     const float* __restrict__ W1,
                     const float* __restrict__ b1,
                     const float* __restrict__ W2,
                     const float* __restrict__ b2,
                     const float* __restrict__ Wo,
                     const float* __restrict__ bo,
                     float* __restrict__ out)
{
    const int l = threadIdx.x;   // 0..63
    const int b = blockIdx.x;    // batch element

    __shared__ float hbuf[64];
    __shared__ float xring[8][64];

    // ---- preload weight columns into registers (192 VGPRs/lane) ----
    float wxa[F_], wxb[F_];
#pragma unroll
    for (int f = 0; f < F_; ++f) {
        wxa[f] = Wx[f * G_ + l];
        wxb[f] = Wx[f * G_ + l + 64];
    }
    float wha[H_], whb[H_];
#pragma unroll
    for (int k = 0; k < H_; ++k) {
        wha[k] = Wh[k * G_ + l];
        whb[k] = Wh[k * G_ + l + 64];
    }
    const float ba = bg[l];
    const float bb = bg[l + 64];

    const float* xb = x + (size_t)b * (S_ * F_);

    hbuf[l] = 0.0f;   // h_0 = 0 (single wave: no barrier needed)

    // prefetch x tiles for t = 0..6 (7 in flight)
    for (int t = 0; t < 7; ++t)
        gload_lds4(xb + t * F_ + l, &xring[t & 7][0]);

    float cc = 0.0f;   // cell state, valid in lanes 32..63 (lane 32+j holds c[j])

    for (int t = 0; t < S_; ++t) {
        // wait until tile t has landed (keep 6 younger loads in flight)
        asm volatile("s_waitcnt vmcnt(6)" ::: "memory");
        {
            int tp = t + 7; if (tp > S_ - 1) tp = S_ - 1;   // clamped: keeps count at 7
            gload_lds4(xb + tp * F_ + l, &xring[(t + 7) & 7][0]);
        }

        float za0 = ba, za1 = 0.0f, zb0 = bb, zb1 = 0.0f;

        // recurrent part: z += h @ Wh   (h broadcast from LDS)
#pragma unroll
        for (int k = 0; k < H_; k += 2) {
            float h0 = hbuf[32 + k];
            float h1 = hbuf[32 + k + 1];
            za0 = fmaf(h0, wha[k],     za0);
            zb0 = fmaf(h0, whb[k],     zb0);
            za1 = fmaf(h1, wha[k + 1], za1);
            zb1 = fmaf(h1, whb[k + 1], zb1);
        }

        // input part: z += x_t @ Wx   (x_t broadcast from LDS ring)
        const float* xt = &xring[t & 7][0];
#pragma unroll
        for (int f = 0; f < F_; f += 2) {
            float x0 = xt[f];
            float x1 = xt[f + 1];
            za0 = fmaf(x0, wxa[f],     za0);
            zb0 = fmaf(x0, wxb[f],     zb0);
            za1 = fmaf(x1, wxa[f + 1], za1);
            zb1 = fmaf(x1, wxb[f + 1], zb1);
        }
        float za = za0 + za1;   // lane<32: i-gate preact ; lane>=32: f-gate preact
        float zb = zb0 + zb1;   // lane<32: g-gate preact ; lane>=32: o-gate preact

        // gate A: sigmoid (all lanes)
        float sa = __builtin_amdgcn_rcpf(1.0f + __expf(-za));
        // gate B: tanh for lanes<32 (g), sigmoid for lanes>=32 (o); tanh(x)=2*sig(2x)-1
        bool lo = (l < 32);
        float zbx = lo ? 2.0f * zb : zb;
        float sb  = __builtin_amdgcn_rcpf(1.0f + __expf(-zbx));
        float rb  = lo ? 2.0f * sb - 1.0f : sb;

        float prod = sa * rb;                 // lanes<32: i*g (lanes>=32: garbage)
        float pr   = __shfl_xor(prod, 32);    // lanes>=32 receive i*g
        cc = fmaf(sa, cc, pr);                // lanes>=32: c = f*c + i*g
        float th = 2.0f * __builtin_amdgcn_rcpf(1.0f + __expf(-2.0f * cc)) - 1.0f;
        float hv = rb * th;                   // lanes>=32: h = o * tanh(c)
        hbuf[l] = hv;                         // hbuf[32+j] = h[j]
    }

    // ---- MLP head: 32 -> 32 -> 16 -> 3, leaky_relu(0.01) between hidden layers ----
    if (l < 32) {
        float a1 = b1[l];
#pragma unroll
        for (int k = 0; k < 32; ++k)
            a1 = fmaf(hbuf[32 + k], W1[k * 32 + l], a1);
        a1 = (a1 > 0.0f) ? a1 : 0.01f * a1;
        hbuf[l] = a1;
    }
    if (l < 16) {
        float a2 = b2[l];
#pragma unroll
        for (int k = 0; k < 32; ++k)
            a2 = fmaf(hbuf[k], W2[k * 16 + l], a2);
        a2 = (a2 > 0.0f) ? a2 : 0.01f * a2;
        hbuf[32 + l] = a2;
    }
    if (l < 3) {
        float o = bo[l];
#pragma unroll
        for (int k = 0; k < 16; ++k)
            o = fmaf(hbuf[32 + k], Wo[k * 3 + l], o);
        out[(size_t)b * 3 + l] = o;
    }
}

extern "C" void kernel_launch(void* const* d_in, const int* in_sizes, int n_in,
                              void* d_out, int out_size, void* d_ws, size_t ws_size,
                              hipStream_t stream) {
    const float* x  = (const float*)d_in[0];
    const float* Wx = (const float*)d_in[1];
    const float* Wh = (const float*)d_in[2];
    const float* bg = (const float*)d_in[3];
    const float* W1 = (const float*)d_in[4];
    const float* b1 = (const float*)d_in[5];
    const float* W2 = (const float*)d_in[6];
    const float* b2 = (const float*)d_in[7];
    const float* Wo = (const float*)d_in[8];
    const float* bo = (const float*)d_in[9];
    float* out = (float*)d_out;

    hipLaunchKernelGGL(lstm_mlp_kernel, dim3(B_), dim3(64), 0, stream,
                       x, Wx, Wh, bg, W1, b1, W2, b2, Wo, bo, out);
}